// Round 3
// baseline (1668.908 us; speedup 1.0000x reference)
//
#include <hip/hip_runtime.h>
#include <hip/hip_bf16.h>
#include <stdint.h>

#define TTOK 32768
#define DDIM 512
#define HDIM 2048
#define NEXP 8
#define GBLK 2048   // gating blocks; 16 tokens per block

typedef __attribute__((ext_vector_type(4))) float f32x4;
typedef __attribute__((ext_vector_type(8))) short bf16x8;

__device__ __forceinline__ ushort f2bf(float f) {
  union { float f; uint32_t u; } cv; cv.f = f;
  uint32_t u = cv.u;
  u = u + 0x7fffu + ((u >> 16) & 1u);
  return (ushort)(u >> 16);
}

__device__ __forceinline__ float bf2f(ushort u) {
  union { uint32_t u; float f; } cv; cv.u = ((uint32_t)u) << 16;
  return cv.f;
}

__device__ __forceinline__ float gelu_tanh(float v) {
  const float c = 0.7978845608028654f;
  float t = tanhf(c * (v + 0.044715f * v * v * v));
  return 0.5f * v * (1.0f + t);
}

// ---------------- weight fp32 -> bf16 convert ----------------
__global__ __launch_bounds__(256) void cvtw_kernel(const float* __restrict__ src,
                                                   ushort* __restrict__ dst, int n4) {
  int i = blockIdx.x * blockDim.x + threadIdx.x;
  if (i >= n4) return;
  float4 v = reinterpret_cast<const float4*>(src)[i];
  ushort4 o;
  o.x = f2bf(v.x); o.y = f2bf(v.y); o.z = f2bf(v.z); o.w = f2bf(v.w);
  reinterpret_cast<ushort4*>(dst)[i] = o;
}

// ---------------- gating ----------------
__global__ __launch_bounds__(256, 4) void gating_kernel(
    const float* __restrict__ x, const float* __restrict__ gw,
    const float* __restrict__ nw, const float* __restrict__ bias,
    const float* __restrict__ noise, ushort* __restrict__ xbf,
    int* __restrict__ cnt, int* __restrict__ idxl,
    int2* __restrict__ slots, float2* __restrict__ tokw,
    float* __restrict__ part) {
  const int tid = threadIdx.x;
  const int lane = tid & 63;
  const int wave = tid >> 6;

  float wg[NEXP][8], wn[NEXP][8];
#pragma unroll
  for (int e = 0; e < NEXP; ++e) {
    const float4* pg = reinterpret_cast<const float4*>(gw + e * DDIM + lane * 8);
    float4 g0 = pg[0], g1 = pg[1];
    wg[e][0] = g0.x; wg[e][1] = g0.y; wg[e][2] = g0.z; wg[e][3] = g0.w;
    wg[e][4] = g1.x; wg[e][5] = g1.y; wg[e][6] = g1.z; wg[e][7] = g1.w;
    const float4* pq = reinterpret_cast<const float4*>(nw + e * DDIM + lane * 8);
    float4 n0 = pq[0], n1 = pq[1];
    wn[e][0] = n0.x; wn[e][1] = n0.y; wn[e][2] = n0.z; wn[e][3] = n0.w;
    wn[e][4] = n1.x; wn[e][5] = n1.y; wn[e][6] = n1.z; wn[e][7] = n1.w;
  }
  float bia[NEXP];
#pragma unroll
  for (int e = 0; e < NEXP; ++e) bia[e] = bias[e];

  float pa_s = 0.f, z_s = 0.f;
  float pm_s[NEXP], imp_s[NEXP], rp_s[NEXP], c1_s[NEXP];
#pragma unroll
  for (int e = 0; e < NEXP; ++e) { pm_s[e] = 0.f; imp_s[e] = 0.f; rp_s[e] = 0.f; c1_s[e] = 0.f; }

  __shared__ int s_i1[16], s_i2[16];
  __shared__ float s_w1[16], s_w2[16];
  __shared__ int lcnt[NEXP], lpos1[16], lpos2[16], gbase[NEXP];

  const int t00 = blockIdx.x * 16 + wave * 4;
  for (int it = 0; it < 4; ++it) {
    const int t = t00 + it;
    const float4* xp = reinterpret_cast<const float4*>(x + (size_t)t * DDIM + lane * 8);
    float4 x0 = xp[0], x1 = xp[1];
    float xv[8] = {x0.x, x0.y, x0.z, x0.w, x1.x, x1.y, x1.z, x1.w};

    ushort4 u0, u1;
    u0.x = f2bf(xv[0]); u0.y = f2bf(xv[1]); u0.z = f2bf(xv[2]); u0.w = f2bf(xv[3]);
    u1.x = f2bf(xv[4]); u1.y = f2bf(xv[5]); u1.z = f2bf(xv[6]); u1.w = f2bf(xv[7]);
    ushort4* xo = reinterpret_cast<ushort4*>(xbf + (size_t)t * DDIM + lane * 8);
    xo[0] = u0; xo[1] = u1;

    float pg[NEXP], pn[NEXP];
#pragma unroll
    for (int e = 0; e < NEXP; ++e) { pg[e] = 0.f; pn[e] = 0.f; }
#pragma unroll
    for (int e = 0; e < NEXP; ++e) {
#pragma unroll
      for (int j = 0; j < 8; ++j) {
        pg[e] = fmaf(xv[j], wg[e][j], pg[e]);
        pn[e] = fmaf(xv[j], wn[e][j], pn[e]);
      }
    }
#pragma unroll
    for (int m = 1; m < 64; m <<= 1) {
#pragma unroll
      for (int e = 0; e < NEXP; ++e) {
        pg[e] += __shfl_xor(pg[e], m);
        pn[e] += __shfl_xor(pn[e], m);
      }
    }
    float sv[NEXP];
#pragma unroll
    for (int e = 0; e < NEXP; ++e) sv[e] = pg[e] * (1.0f / 1.66f);
    float mx = sv[0];
#pragma unroll
    for (int e = 1; e < NEXP; ++e) mx = fmaxf(mx, sv[e]);
    float ssum = 0.f, pvals[NEXP];
#pragma unroll
    for (int e = 0; e < NEXP; ++e) { pvals[e] = expf(sv[e] - mx); ssum += pvals[e]; }
    float sinv = 1.f / ssum;
#pragma unroll
    for (int e = 0; e < NEXP; ++e) {
      float pe = pvals[e] * sinv;
      pa_s += pe * (1.f - pe);
      pm_s[e] += pe;
    }
    float mg = pg[0];
#pragma unroll
    for (int e = 1; e < NEXP; ++e) mg = fmaxf(mg, pg[e]);
    float es2 = 0.f;
#pragma unroll
    for (int e = 0; e < NEXP; ++e) es2 += expf(pg[e] - mg);
    float lse = mg + logf(es2);
    z_s += lse * lse;
    float g2[NEXP];
#pragma unroll
    for (int e = 0; e < NEXP; ++e) {
      float s = pn[e];
      float sp = fmaxf(s, 0.f) + log1pf(expf(-fabsf(s)));
      g2[e] = pg[e] + noise[(size_t)t * NEXP + e] * sp + bia[e];
    }
    float v1 = g2[0]; int i1 = 0;
#pragma unroll
    for (int e = 1; e < NEXP; ++e) if (g2[e] > v1) { v1 = g2[e]; i1 = e; }
    float v2 = -3.4e38f; int i2 = 0;
#pragma unroll
    for (int e = 0; e < NEXP; ++e) if (e != i1 && g2[e] > v2) { v2 = g2[e]; i2 = e; }
    float dd = expf(v2 - v1);
    float w1 = 1.f / (1.f + dd);
    float w2 = dd / (1.f + dd);
    float mr = g2[0];
#pragma unroll
    for (int e = 1; e < NEXP; ++e) mr = fmaxf(mr, g2[e]);
    float rs = 0.f, er[NEXP];
#pragma unroll
    for (int e = 0; e < NEXP; ++e) { er[e] = expf(g2[e] - mr); rs += er[e]; }
    float rinv = 1.f / rs;
#pragma unroll
    for (int e = 0; e < NEXP; ++e) rp_s[e] += er[e] * rinv;
#pragma unroll
    for (int e = 0; e < NEXP; ++e) {
      imp_s[e] += (e == i1 ? w1 : 0.f) + (e == i2 ? w2 : 0.f);
      c1_s[e] += (e == i1) ? 1.f : 0.f;
    }
    if (lane == 0) {
      int k = wave * 4 + it;
      s_i1[k] = i1; s_i2[k] = i2; s_w1[k] = w1; s_w2[k] = w2;
    }
  }

  __shared__ float red[4][34];
  if (lane == 0) {
    red[wave][0] = pa_s; red[wave][1] = z_s;
#pragma unroll
    for (int e = 0; e < NEXP; ++e) {
      red[wave][2 + e] = pm_s[e];
      red[wave][10 + e] = imp_s[e];
      red[wave][18 + e] = rp_s[e];
      red[wave][26 + e] = c1_s[e];
    }
  }
  if (tid < NEXP) lcnt[tid] = 0;
  __syncthreads();
  if (tid < 34) {
    float s = red[0][tid] + red[1][tid] + red[2][tid] + red[3][tid];
    part[(size_t)tid * GBLK + blockIdx.x] = s;
  }
  if (tid < 16) {
    lpos1[tid] = atomicAdd(&lcnt[s_i1[tid]], 1);
    lpos2[tid] = atomicAdd(&lcnt[s_i2[tid]], 1);
  }
  __syncthreads();
  if (tid < NEXP) gbase[tid] = atomicAdd(&cnt[tid], lcnt[tid]);
  __syncthreads();
  if (tid < 16) {
    int t = blockIdx.x * 16 + tid;
    int e1 = s_i1[tid], p1 = gbase[e1] + lpos1[tid];
    int e2 = s_i2[tid], p2 = gbase[e2] + lpos2[tid];
    idxl[e1 * TTOK + p1] = t;
    idxl[e2 * TTOK + p2] = t;
    slots[t] = make_int2((e1 << 16) | p1, (e2 << 16) | p2);
    tokw[t] = make_float2(s_w1[tid], s_w2[tid]);
  }
}

// ---------------- finalize: aux + offsets + list padding ----------------
__global__ __launch_bounds__(256) void finalize_kernel(
    const float* __restrict__ part, const int* __restrict__ cnt,
    int* __restrict__ offs, int* __restrict__ idxl,
    float* __restrict__ aux_out) {
  __shared__ float sums[34];
  __shared__ float red[4][34];
  __shared__ int roundc[NEXP], base[NEXP];
  const int tid = threadIdx.x;
  const int lane = tid & 63, wave = tid >> 6;

  float loc[34];
#pragma unroll
  for (int s = 0; s < 34; ++s) loc[s] = 0.f;
  for (int b = tid; b < GBLK; b += 256) {
#pragma unroll
    for (int s = 0; s < 34; ++s) loc[s] += part[(size_t)s * GBLK + b];
  }
#pragma unroll
  for (int m = 1; m < 64; m <<= 1) {
#pragma unroll
    for (int s = 0; s < 34; ++s) loc[s] += __shfl_xor(loc[s], m);
  }
  if (lane == 0) {
#pragma unroll
    for (int s = 0; s < 34; ++s) red[wave][s] = loc[s];
  }
  if (tid == 0) {
    int acc = 0;
    for (int e = 0; e < NEXP; ++e) {
      int r = (cnt[e] + 127) & ~127;
      roundc[e] = r; base[e] = acc; acc += r;
    }
  }
  __syncthreads();
  if (tid < 34) sums[tid] = red[0][tid] + red[1][tid] + red[2][tid] + red[3][tid];
  __syncthreads();
  for (int i = tid; i < NEXP * 128; i += 256) {
    int e = i >> 7, k = i & 127;
    int pos = cnt[e] + k;
    if (pos < roundc[e]) idxl[e * TTOK + pos] = 0;
  }
  if (tid < NEXP) offs[tid] = base[tid];
  if (tid == 0) {
    const float Tf = (float)TTOK;
    float pa = sums[0] / (Tf * 8.f);
    float pbm = 0.f;
    for (int e = 0; e < NEXP; ++e) { float pm = sums[2 + e] / Tf; pbm += pm * (1.f - pm); }
    float pb = 1.f / 8.f - pbm / 8.f;
    float penalty = (pa + pb) * 0.01f;
    float z = 0.001f * sums[1] / Tf;
    float mean = 0.f;
    for (int e = 0; e < NEXP; ++e) mean += sums[10 + e];
    mean /= 8.f;
    float var = 0.f;
    for (int e = 0; e < NEXP; ++e) { float d = sums[10 + e] - mean; var += d * d; }
    var /= 8.f;
    float il = 0.01f * var / (mean * mean);
    float ld = 0.f;
    for (int e = 0; e < NEXP; ++e) ld += (sums[26 + e] / Tf) * (sums[18 + e] / Tf);
    ld *= 0.01f * 8.f;
    aux_out[0] = penalty + z + il + ld;
  }
}

// ---------------- GEMM1: h = gelu(x[idx] @ Wfc^T + b) ----------------
__global__ __launch_bounds__(256, 2) void gemm1_kernel(
    const ushort* __restrict__ xbf, const ushort* __restrict__ wfc,
    const float* __restrict__ fcb, const int* __restrict__ idxl,
    const int* __restrict__ cnt, const int* __restrict__ offs,
    ushort* __restrict__ h, int hbase, int HC) {
  const int e = blockIdx.z;
  const int count = cnt[e];
  const int rounded = (count + 127) & ~127;
  const int mt = blockIdx.x;
  if (mt * 128 >= rounded) return;
  const int nt = blockIdx.y;
  const int tid = threadIdx.x;
  const int lane = tid & 63, wave = tid >> 6;
  const int wm = wave >> 1, wn = wave & 1;

  __shared__ ushort As[2][128][72];
  __shared__ ushort Bs[2][128][72];

  const int srow = tid >> 3;
  const int sk = (tid & 7) * 8;

  const ushort* aptr[4];
  const ushort* bptr[4];
#pragma unroll
  for (int r = 0; r < 4; ++r) {
    int row = srow + r * 32;
    int g = idxl[e * TTOK + mt * 128 + row];
    aptr[r] = xbf + (size_t)g * DDIM + sk;
    int hrow = hbase + nt * 128 + row;
    bptr[r] = wfc + (size_t)e * (HDIM * DDIM) + (size_t)hrow * DDIM + sk;
  }

  f32x4 acc[4][4];
#pragma unroll
  for (int m = 0; m < 4; ++m)
#pragma unroll
    for (int n = 0; n < 4; ++n)
      acc[m][n] = (f32x4){0.f, 0.f, 0.f, 0.f};

  uint4 ra[4], rb[4];
#pragma unroll
  for (int r = 0; r < 4; ++r) {
    ra[r] = *reinterpret_cast<const uint4*>(aptr[r]);
    rb[r] = *reinterpret_cast<const uint4*>(bptr[r]);
  }
#pragma unroll
  for (int r = 0; r < 4; ++r) {
    *reinterpret_cast<uint4*>(&As[0][srow + r * 32][sk]) = ra[r];
    *reinterpret_cast<uint4*>(&Bs[0][srow + r * 32][sk]) = rb[r];
  }
  __syncthreads();

  const int NK = DDIM / 64;
  for (int kt = 0; kt < NK; ++kt) {
    const int cur = kt & 1;
    if (kt + 1 < NK) {
#pragma unroll
      for (int r = 0; r < 4; ++r) {
        ra[r] = *reinterpret_cast<const uint4*>(aptr[r] + (kt + 1) * 64);
        rb[r] = *reinterpret_cast<const uint4*>(bptr[r] + (kt + 1) * 64);
      }
    }
#pragma unroll
    for (int ks = 0; ks < 2; ++ks) {
      bf16x8 af[4], bfr[4];
#pragma unroll
      for (int m = 0; m < 4; ++m)
        af[m] = *reinterpret_cast<const bf16x8*>(&As[cur][wm * 64 + m * 16 + (lane & 15)][ks * 32 + (lane >> 4) * 8]);
#pragma unroll
      for (int n = 0; n < 4; ++n)
        bfr[n] = *reinterpret_cast<const bf16x8*>(&Bs[cur][wn * 64 + n * 16 + (lane & 15)][ks * 32 + (lane >> 4) * 8]);
#pragma unroll
      for (int m = 0; m < 4; ++m)
#pragma unroll
        for (int n = 0; n < 4; ++n)
          acc[m][n] = __builtin_amdgcn_mfma_f32_16x16x32_bf16(af[m], bfr[n], acc[m][n], 0, 0, 0);
    }
    if (kt + 1 < NK) {
#pragma unroll
      for (int r = 0; r < 4; ++r) {
        *reinterpret_cast<uint4*>(&As[(kt + 1) & 1][srow + r * 32][sk]) = ra[r];
        *reinterpret_cast<uint4*>(&Bs[(kt + 1) & 1][srow + r * 32][sk]) = rb[r];
      }
      __syncthreads();
    }
  }

  const int hb = offs[e];
#pragma unroll
  for (int n = 0; n < 4; ++n) {
    const int col = wn * 64 + n * 16 + (lane & 15);
    const int gcol = hbase + nt * 128 + col;
    const float bterm = fcb[e * HDIM + gcol];
#pragma unroll
    for (int m = 0; m < 4; ++m) {
#pragma unroll
      for (int j = 0; j < 4; ++j) {
        const int row = mt * 128 + wm * 64 + m * 16 + ((lane >> 4) << 2) + j;
        float v = acc[m][n][j] + bterm;
        h[(size_t)(hb + row) * HC + (nt * 128 + col)] = f2bf(gelu_tanh(v));
      }
    }
  }
}

// ---------------- GEMM2: scratch[slot] = h @ Wproj^T + b (plain stores) ----------------
__global__ __launch_bounds__(256, 2) void gemm2_kernel(
    const ushort* __restrict__ h, const ushort* __restrict__ wpj,
    const float* __restrict__ pjb, const int* __restrict__ cnt,
    const int* __restrict__ offs, ushort* __restrict__ scratch,
    int hbase, int HC, int first_chunk) {
  const int e = blockIdx.z;
  const int count = cnt[e];
  const int rounded = (count + 127) & ~127;
  const int mt = blockIdx.x;
  if (mt * 128 >= rounded) return;
  const int nt = blockIdx.y;
  const int tid = threadIdx.x;
  const int lane = tid & 63, wave = tid >> 6;
  const int wm = wave >> 1, wn = wave & 1;

  __shared__ ushort As[2][128][72];
  __shared__ ushort Bs[2][128][72];

  const int srow = tid >> 3;
  const int sk = (tid & 7) * 8;
  const int hb = offs[e];

  const ushort* aptr[4];
  const ushort* bptr[4];
#pragma unroll
  for (int r = 0; r < 4; ++r) {
    int row = srow + r * 32;
    aptr[r] = h + (size_t)(hb + mt * 128 + row) * HC + sk;
    bptr[r] = wpj + (size_t)e * (DDIM * HDIM) + (size_t)(nt * 128 + row) * HDIM + hbase + sk;
  }

  f32x4 acc[4][4];
#pragma unroll
  for (int m = 0; m < 4; ++m)
#pragma unroll
    for (int n = 0; n < 4; ++n)
      acc[m][n] = (f32x4){0.f, 0.f, 0.f, 0.f};

  uint4 ra[4], rb[4];
#pragma unroll
  for (int r = 0; r < 4; ++r) {
    ra[r] = *reinterpret_cast<const uint4*>(aptr[r]);
    rb[r] = *reinterpret_cast<const uint4*>(bptr[r]);
  }
#pragma unroll
  for (int r = 0; r < 4; ++r) {
    *reinterpret_cast<uint4*>(&As[0][srow + r * 32][sk]) = ra[r];
    *reinterpret_cast<uint4*>(&Bs[0][srow + r * 32][sk]) = rb[r];
  }
  __syncthreads();

  const int NK = HC / 64;
  for (int kt = 0; kt < NK; ++kt) {
    const int cur = kt & 1;
    if (kt + 1 < NK) {
#pragma unroll
      for (int r = 0; r < 4; ++r) {
        ra[r] = *reinterpret_cast<const uint4*>(aptr[r] + (kt + 1) * 64);
        rb[r] = *reinterpret_cast<const uint4*>(bptr[r] + (kt + 1) * 64);
      }
    }
#pragma unroll
    for (int ks = 0; ks < 2; ++ks) {
      bf16x8 af[4], bfr[4];
#pragma unroll
      for (int m = 0; m < 4; ++m)
        af[m] = *reinterpret_cast<const bf16x8*>(&As[cur][wm * 64 + m * 16 + (lane & 15)][ks * 32 + (lane >> 4) * 8]);
#pragma unroll
      for (int n = 0; n < 4; ++n)
        bfr[n] = *reinterpret_cast<const bf16x8*>(&Bs[cur][wn * 64 + n * 16 + (lane & 15)][ks * 32 + (lane >> 4) * 8]);
#pragma unroll
      for (int m = 0; m < 4; ++m)
#pragma unroll
        for (int n = 0; n < 4; ++n)
          acc[m][n] = __builtin_amdgcn_mfma_f32_16x16x32_bf16(af[m], bfr[n], acc[m][n], 0, 0, 0);
    }
    if (kt + 1 < NK) {
#pragma unroll
      for (int r = 0; r < 4; ++r) {
        *reinterpret_cast<uint4*>(&As[(kt + 1) & 1][srow + r * 32][sk]) = ra[r];
        *reinterpret_cast<uint4*>(&Bs[(kt + 1) & 1][srow + r * 32][sk]) = rb[r];
      }
      __syncthreads();
    }
  }

#pragma unroll
  for (int n = 0; n < 4; ++n) {
    const int col = nt * 128 + wn * 64 + n * 16 + (lane & 15);
    const float bterm = pjb[e * DDIM + col];
#pragma unroll
    for (int m = 0; m < 4; ++m) {
#pragma unroll
      for (int j = 0; j < 4; ++j) {
        const size_t row = (size_t)(hb + mt * 128 + wm * 64 + m * 16 + ((lane >> 4) << 2) + j);
        ushort* p = scratch + row * DDIM + col;
        float v = acc[m][n][j];
        if (first_chunk) v += bterm;
        else v += bf2f(*p);
        *p = f2bf(v);
      }
    }
  }
}

// ---------------- combine: out[t] = w1*row1 + w2*row2 ----------------
__global__ __launch_bounds__(256, 8) void combine_kernel(
    const ushort* __restrict__ scratch, const int* __restrict__ offs,
    const int2* __restrict__ slots, const float2* __restrict__ tokw,
    float* __restrict__ out) {
  const int lane = threadIdx.x & 63;
  const int wave = threadIdx.x >> 6;
  const int t = blockIdx.x * 4 + wave;
  int2 s = slots[t];
  float2 w = tokw[t];
  const int r1 = offs[s.x >> 16] + (s.x & 0xFFFF);
  const int r2 = offs[s.y >> 16] + (s.y & 0xFFFF);
  bf16x8 a = *reinterpret_cast<const bf16x8*>(scratch + (size_t)r1 * DDIM + lane * 8);
  bf16x8 b = *reinterpret_cast<const bf16x8*>(scratch + (size_t)r2 * DDIM + lane * 8);
  float r[8];
#pragma unroll
  for (int j = 0; j < 8; ++j)
    r[j] = w.x * bf2f((ushort)a[j]) + w.y * bf2f((ushort)b[j]);
  float4* op = reinterpret_cast<float4*>(out + (size_t)t * DDIM + lane * 8);
  op[0] = make_float4(r[0], r[1], r[2], r[3]);
  op[1] = make_float4(r[4], r[5], r[6], r[7]);
}

extern "C" void kernel_launch(void* const* d_in, const int* in_sizes, int n_in,
                              void* d_out, int out_size, void* d_ws, size_t ws_size,
                              hipStream_t stream) {
  const float* x    = (const float*)d_in[0];
  const float* gw   = (const float*)d_in[1];
  const float* nw   = (const float*)d_in[2];
  const float* bias = (const float*)d_in[3];
  const float* fcw  = (const float*)d_in[4];
  const float* fcb  = (const float*)d_in[5];
  const float* pjw  = (const float*)d_in[6];
  const float* pjb  = (const float*)d_in[7];
  const float* noise = (const float*)d_in[8];
  float* out = (float*)d_out;

  char* ws = (char*)d_ws;
  size_t o = 0;
  auto alloc = [&](size_t bytes) -> char* {
    char* p = ws + o;
    o += (bytes + 255) & ~(size_t)255;
    return p;
  };
  ushort* xbf   = (ushort*)alloc((size_t)TTOK * DDIM * 2);
  ushort* wfcb  = (ushort*)alloc((size_t)NEXP * HDIM * DDIM * 2);
  ushort* wpjb  = (ushort*)alloc((size_t)NEXP * DDIM * HDIM * 2);
  int*    idxl  = (int*)alloc((size_t)NEXP * TTOK * 4);
  int2*   slots = (int2*)alloc((size_t)TTOK * 8);
  float2* tokw  = (float2*)alloc((size_t)TTOK * 8);
  int*    cnt   = (int*)alloc(256);
  int*    offs  = (int*)alloc(256);
  float*  part  = (float*)alloc(34 * GBLK * 4);
  ushort* scr   = (ushort*)alloc((size_t)(2 * TTOK + 1024) * DDIM * 2);
  size_t fixed = o;

  int NCH = 16;
  const int chs[5] = {1, 2, 4, 8, 16};
  for (int ci = 0; ci < 5; ++ci) {
    size_t need = fixed + (size_t)(2 * TTOK + 1024) * (size_t)(HDIM / chs[ci]) * 2;
    if (need <= ws_size) { NCH = chs[ci]; break; }
  }
  const int HC = HDIM / NCH;
  ushort* h = (ushort*)alloc((size_t)(2 * TTOK + 1024) * HC * 2);

  hipMemsetAsync(cnt, 0, 32, stream);

  cvtw_kernel<<<8192, 256, 0, stream>>>(fcw, wfcb, NEXP * HDIM * DDIM / 4);
  cvtw_kernel<<<8192, 256, 0, stream>>>(pjw, wpjb, NEXP * DDIM * HDIM / 4);
  gating_kernel<<<GBLK, 256, 0, stream>>>(x, gw, nw, bias, noise, xbf, cnt, idxl, slots, tokw, part);
  finalize_kernel<<<1, 256, 0, stream>>>(part, cnt, offs, idxl, out + ((size_t)out_size - 1));

  for (int c = 0; c < NCH; ++c) {
    gemm1_kernel<<<dim3(256, HC / 128, NEXP), 256, 0, stream>>>(
        xbf, wfcb, fcb, idxl, cnt, offs, h, c * HC, HC);
    gemm2_kernel<<<dim3(256, 4, NEXP), 256, 0, stream>>>(
        h, wpjb, pjb, cnt, offs, scr, c * HC, HC, c == 0);
  }
  combine_kernel<<<TTOK / 4, 256, 0, stream>>>(scr, offs, slots, tokw, out);
}

// Round 4
// 931.377 us; speedup vs baseline: 1.7919x; 1.7919x over previous
//
#include <hip/hip_runtime.h>
#include <hip/hip_bf16.h>
#include <stdint.h>

#define TTOK 32768
#define DDIM 512
#define HDIM 2048
#define NEXP 8
#define GBLK 1024   // gating blocks; 32 tokens per block (8 per wave)

typedef __attribute__((ext_vector_type(4))) float f32x4;
typedef __attribute__((ext_vector_type(8))) short bf16x8;

#define GLOAD16(gp, lp)                                                      \
  __builtin_amdgcn_global_load_lds(                                          \
      (const __attribute__((address_space(1))) unsigned int*)(gp),           \
      (__attribute__((address_space(3))) unsigned int*)(lp), 16, 0, 0)

__device__ __forceinline__ ushort f2bf(float f) {
  union { float f; uint32_t u; } cv; cv.f = f;
  uint32_t u = cv.u;
  u = u + 0x7fffu + ((u >> 16) & 1u);
  return (ushort)(u >> 16);
}

__device__ __forceinline__ float bf2f(ushort u) {
  union { uint32_t u; float f; } cv; cv.u = ((uint32_t)u) << 16;
  return cv.f;
}

__device__ __forceinline__ float gelu_tanh(float v) {
  const float c = 0.7978845608028654f;
  float t = tanhf(c * (v + 0.044715f * v * v * v));
  return 0.5f * v * (1.0f + t);
}

// ---------------- weight fp32 -> bf16 convert ----------------
__global__ __launch_bounds__(256) void cvtw_kernel(const float* __restrict__ src,
                                                   ushort* __restrict__ dst, int n4) {
  int i = blockIdx.x * blockDim.x + threadIdx.x;
  if (i >= n4) return;
  float4 v = reinterpret_cast<const float4*>(src)[i];
  ushort4 o;
  o.x = f2bf(v.x); o.y = f2bf(v.y); o.z = f2bf(v.z); o.w = f2bf(v.w);
  reinterpret_cast<ushort4*>(dst)[i] = o;
}

// ---------------- gating ----------------
// launch_bounds(256,2): VGPR cap 256 so wg/wn (128 regs) stay resident.
// Round-2/3 used (256,4) -> cap 128 -> spill -> 895 MB scratch traffic.
__global__ __launch_bounds__(256, 2) void gating_kernel(
    const float* __restrict__ x, const float* __restrict__ gw,
    const float* __restrict__ nw, const float* __restrict__ bias,
    const float* __restrict__ noise, ushort* __restrict__ xbf,
    int* __restrict__ cnt, int* __restrict__ idxl,
    int2* __restrict__ slots, float2* __restrict__ tokw,
    float* __restrict__ part) {
  const int tid = threadIdx.x;
  const int lane = tid & 63;
  const int wave = tid >> 6;

  float wg[NEXP][8], wn[NEXP][8];
#pragma unroll
  for (int e = 0; e < NEXP; ++e) {
    const float4* pg = reinterpret_cast<const float4*>(gw + e * DDIM + lane * 8);
    float4 g0 = pg[0], g1 = pg[1];
    wg[e][0] = g0.x; wg[e][1] = g0.y; wg[e][2] = g0.z; wg[e][3] = g0.w;
    wg[e][4] = g1.x; wg[e][5] = g1.y; wg[e][6] = g1.z; wg[e][7] = g1.w;
    const float4* pq = reinterpret_cast<const float4*>(nw + e * DDIM + lane * 8);
    float4 n0 = pq[0], n1 = pq[1];
    wn[e][0] = n0.x; wn[e][1] = n0.y; wn[e][2] = n0.z; wn[e][3] = n0.w;
    wn[e][4] = n1.x; wn[e][5] = n1.y; wn[e][6] = n1.z; wn[e][7] = n1.w;
  }
  float bia[NEXP];
#pragma unroll
  for (int e = 0; e < NEXP; ++e) bia[e] = bias[e];

  float pa_s = 0.f, z_s = 0.f;
  float pm_s[NEXP], imp_s[NEXP], rp_s[NEXP], c1_s[NEXP];
#pragma unroll
  for (int e = 0; e < NEXP; ++e) { pm_s[e] = 0.f; imp_s[e] = 0.f; rp_s[e] = 0.f; c1_s[e] = 0.f; }

  __shared__ int s_i1[32], s_i2[32];
  __shared__ float s_w1[32], s_w2[32];
  __shared__ int lcnt[NEXP], lpos1[32], lpos2[32], gbase[NEXP];

  const int t00 = blockIdx.x * 32 + wave * 8;
  for (int it = 0; it < 8; ++it) {
    const int t = t00 + it;
    const float4* xp = reinterpret_cast<const float4*>(x + (size_t)t * DDIM + lane * 8);
    float4 x0 = xp[0], x1 = xp[1];
    float xv[8] = {x0.x, x0.y, x0.z, x0.w, x1.x, x1.y, x1.z, x1.w};

    ushort u8[8];
#pragma unroll
    for (int j = 0; j < 8; ++j) u8[j] = f2bf(xv[j]);
    uint4 pack;
    pack.x = (uint32_t)u8[0] | ((uint32_t)u8[1] << 16);
    pack.y = (uint32_t)u8[2] | ((uint32_t)u8[3] << 16);
    pack.z = (uint32_t)u8[4] | ((uint32_t)u8[5] << 16);
    pack.w = (uint32_t)u8[6] | ((uint32_t)u8[7] << 16);
    *reinterpret_cast<uint4*>(xbf + (size_t)t * DDIM + lane * 8) = pack;

    float pg[NEXP], pn[NEXP];
#pragma unroll
    for (int e = 0; e < NEXP; ++e) { pg[e] = 0.f; pn[e] = 0.f; }
#pragma unroll
    for (int e = 0; e < NEXP; ++e) {
#pragma unroll
      for (int j = 0; j < 8; ++j) {
        pg[e] = fmaf(xv[j], wg[e][j], pg[e]);
        pn[e] = fmaf(xv[j], wn[e][j], pn[e]);
      }
    }
#pragma unroll
    for (int m = 1; m < 64; m <<= 1) {
#pragma unroll
      for (int e = 0; e < NEXP; ++e) {
        pg[e] += __shfl_xor(pg[e], m);
        pn[e] += __shfl_xor(pn[e], m);
      }
    }
    // penalty softmax (temperature) - aux only, fast exp fine
    float sv[NEXP];
#pragma unroll
    for (int e = 0; e < NEXP; ++e) sv[e] = pg[e] * (1.0f / 1.66f);
    float mx = sv[0];
#pragma unroll
    for (int e = 1; e < NEXP; ++e) mx = fmaxf(mx, sv[e]);
    float ssum = 0.f, pvals[NEXP];
#pragma unroll
    for (int e = 0; e < NEXP; ++e) { pvals[e] = __expf(sv[e] - mx); ssum += pvals[e]; }
    float sinv = 1.f / ssum;
#pragma unroll
    for (int e = 0; e < NEXP; ++e) {
      float pe = pvals[e] * sinv;
      pa_s += pe * (1.f - pe);
      pm_s[e] += pe;
    }
    // logsumexp of clean logits - aux only
    float mg = pg[0];
#pragma unroll
    for (int e = 1; e < NEXP; ++e) mg = fmaxf(mg, pg[e]);
    float es2 = 0.f;
#pragma unroll
    for (int e = 0; e < NEXP; ++e) es2 += __expf(pg[e] - mg);
    float lse = mg + __logf(es2);
    z_s += lse * lse;
    // noisy logits: softplus kept precise (feeds top-2 selection)
    float g2[NEXP];
#pragma unroll
    for (int e = 0; e < NEXP; ++e) {
      float s = pn[e];
      float sp = fmaxf(s, 0.f) + log1pf(expf(-fabsf(s)));
      g2[e] = pg[e] + noise[(size_t)t * NEXP + e] * sp + bia[e];
    }
    float v1 = g2[0]; int i1 = 0;
#pragma unroll
    for (int e = 1; e < NEXP; ++e) if (g2[e] > v1) { v1 = g2[e]; i1 = e; }
    float v2 = -3.4e38f; int i2 = 0;
#pragma unroll
    for (int e = 0; e < NEXP; ++e) if (e != i1 && g2[e] > v2) { v2 = g2[e]; i2 = e; }
    float dd = __expf(v2 - v1);
    float w1 = 1.f / (1.f + dd);
    float w2 = dd / (1.f + dd);
    float mr = g2[0];
#pragma unroll
    for (int e = 1; e < NEXP; ++e) mr = fmaxf(mr, g2[e]);
    float rs = 0.f, er[NEXP];
#pragma unroll
    for (int e = 0; e < NEXP; ++e) { er[e] = __expf(g2[e] - mr); rs += er[e]; }
    float rinv = 1.f / rs;
#pragma unroll
    for (int e = 0; e < NEXP; ++e) rp_s[e] += er[e] * rinv;
#pragma unroll
    for (int e = 0; e < NEXP; ++e) {
      imp_s[e] += (e == i1 ? w1 : 0.f) + (e == i2 ? w2 : 0.f);
      c1_s[e] += (e == i1) ? 1.f : 0.f;
    }
    if (lane == 0) {
      int k = wave * 8 + it;
      s_i1[k] = i1; s_i2[k] = i2; s_w1[k] = w1; s_w2[k] = w2;
    }
  }

  __shared__ float red[4][34];
  if (lane == 0) {
    red[wave][0] = pa_s; red[wave][1] = z_s;
#pragma unroll
    for (int e = 0; e < NEXP; ++e) {
      red[wave][2 + e] = pm_s[e];
      red[wave][10 + e] = imp_s[e];
      red[wave][18 + e] = rp_s[e];
      red[wave][26 + e] = c1_s[e];
    }
  }
  if (tid < NEXP) lcnt[tid] = 0;
  __syncthreads();
  if (tid < 34) {
    float s = red[0][tid] + red[1][tid] + red[2][tid] + red[3][tid];
    part[(size_t)tid * GBLK + blockIdx.x] = s;
  }
  if (tid < 32) {
    lpos1[tid] = atomicAdd(&lcnt[s_i1[tid]], 1);
    lpos2[tid] = atomicAdd(&lcnt[s_i2[tid]], 1);
  }
  __syncthreads();
  if (tid < NEXP) gbase[tid] = atomicAdd(&cnt[tid], lcnt[tid]);
  __syncthreads();
  if (tid < 32) {
    int t = blockIdx.x * 32 + tid;
    int e1 = s_i1[tid], p1 = gbase[e1] + lpos1[tid];
    int e2 = s_i2[tid], p2 = gbase[e2] + lpos2[tid];
    idxl[e1 * TTOK + p1] = t;
    idxl[e2 * TTOK + p2] = t;
    slots[t] = make_int2((e1 << 16) | p1, (e2 << 16) | p2);
    tokw[t] = make_float2(s_w1[tid], s_w2[tid]);
  }
}

// ---------------- finalize: aux + offsets + list padding ----------------
__global__ __launch_bounds__(256) void finalize_kernel(
    const float* __restrict__ part, const int* __restrict__ cnt,
    int* __restrict__ offs, int* __restrict__ idxl,
    float* __restrict__ aux_out) {
  __shared__ float sums[34];
  __shared__ float red[4][34];
  __shared__ int roundc[NEXP], base[NEXP];
  const int tid = threadIdx.x;
  const int lane = tid & 63, wave = tid >> 6;

  float loc[34];
#pragma unroll
  for (int s = 0; s < 34; ++s) loc[s] = 0.f;
  for (int b = tid; b < GBLK; b += 256) {
#pragma unroll
    for (int s = 0; s < 34; ++s) loc[s] += part[(size_t)s * GBLK + b];
  }
#pragma unroll
  for (int m = 1; m < 64; m <<= 1) {
#pragma unroll
    for (int s = 0; s < 34; ++s) loc[s] += __shfl_xor(loc[s], m);
  }
  if (lane == 0) {
#pragma unroll
    for (int s = 0; s < 34; ++s) red[wave][s] = loc[s];
  }
  if (tid == 0) {
    int acc = 0;
    for (int e = 0; e < NEXP; ++e) {
      int r = (cnt[e] + 127) & ~127;
      roundc[e] = r; base[e] = acc; acc += r;
    }
  }
  __syncthreads();
  if (tid < 34) sums[tid] = red[0][tid] + red[1][tid] + red[2][tid] + red[3][tid];
  __syncthreads();
  for (int i = tid; i < NEXP * 128; i += 256) {
    int e = i >> 7, k = i & 127;
    int pos = cnt[e] + k;
    if (pos < roundc[e]) idxl[e * TTOK + pos] = 0;
  }
  if (tid < NEXP) offs[tid] = base[tid];
  if (tid == 0) {
    const float Tf = (float)TTOK;
    float pa = sums[0] / (Tf * 8.f);
    float pbm = 0.f;
    for (int e = 0; e < NEXP; ++e) { float pm = sums[2 + e] / Tf; pbm += pm * (1.f - pm); }
    float pb = 1.f / 8.f - pbm / 8.f;
    float penalty = (pa + pb) * 0.01f;
    float z = 0.001f * sums[1] / Tf;
    float mean = 0.f;
    for (int e = 0; e < NEXP; ++e) mean += sums[10 + e];
    mean /= 8.f;
    float var = 0.f;
    for (int e = 0; e < NEXP; ++e) { float d = sums[10 + e] - mean; var += d * d; }
    var /= 8.f;
    float il = 0.01f * var / (mean * mean);
    float ld = 0.f;
    for (int e = 0; e < NEXP; ++e) ld += (sums[26 + e] / Tf) * (sums[18 + e] / Tf);
    ld *= 0.01f * 8.f;
    aux_out[0] = penalty + z + il + ld;
  }
}

// ============ GEMM kernels: global_load_lds + XOR-swizzled LDS, 2-phase ======
// LDS layout: [128][64] ushort, linear (no pad). Slot s of row r holds global
// K-chunk (s ^ (r&7)) (16B chunks). Staged by pre-swizzling the GLOBAL source
// chunk; ds_read applies the same XOR. (both-sides-or-neither, m201 pattern)

// ---------------- GEMM1: h = gelu(x[idx] @ Wfc^T + b) ----------------
__global__ __launch_bounds__(256, 2) void gemm1_kernel(
    const ushort* __restrict__ xbf, const ushort* __restrict__ wfc,
    const float* __restrict__ fcb, const int* __restrict__ idxl,
    const int* __restrict__ cnt, const int* __restrict__ offs,
    ushort* __restrict__ h, int hbase, int HC) {
  const int e = blockIdx.z;
  const int count = cnt[e];
  const int rounded = (count + 127) & ~127;
  const int mt = blockIdx.x;
  if (mt * 128 >= rounded) return;
  const int nt = blockIdx.y;
  const int tid = threadIdx.x;
  const int lane = tid & 63, wave = tid >> 6;
  const int wm = wave >> 1, wn = wave & 1;

  __shared__ ushort As[2][128][64];
  __shared__ ushort Bs[2][128][64];

  const int srow = tid >> 3;                      // staging row 0..31
  const int csw8 = (((tid & 7) ^ (srow & 7)) << 3);  // swizzled global chunk (ushorts)
  const int dst8 = ((tid & 7) << 3);                 // linear LDS chunk (ushorts)

  int gA[4];
  const ushort* bbase = wfc + (size_t)e * (HDIM * DDIM) +
                        (size_t)(hbase + nt * 128) * DDIM;
#pragma unroll
  for (int r = 0; r < 4; ++r)
    gA[r] = idxl[e * TTOK + mt * 128 + srow + r * 32];

  f32x4 acc[4][4];
#pragma unroll
  for (int m = 0; m < 4; ++m)
#pragma unroll
    for (int n = 0; n < 4; ++n)
      acc[m][n] = (f32x4){0.f, 0.f, 0.f, 0.f};

#define G1_STAGE(buf, kt)                                                     \
  {                                                                           \
    const int koff = (kt) * 64;                                               \
    _Pragma("unroll") for (int r = 0; r < 4; ++r) {                           \
      GLOAD16(xbf + (size_t)gA[r] * DDIM + koff + csw8,                       \
              &As[buf][srow + r * 32][dst8]);                                 \
      GLOAD16(bbase + (size_t)(srow + r * 32) * DDIM + koff + csw8,           \
              &Bs[buf][srow + r * 32][dst8]);                                 \
    }                                                                         \
  }

  G1_STAGE(0, 0);
  asm volatile("s_waitcnt vmcnt(0)" ::: "memory");
  __syncthreads();

  const int NK = DDIM / 64;
  for (int kt = 0; kt < NK; ++kt) {
    const int cur = kt & 1;
    if (kt + 1 < NK) G1_STAGE(cur ^ 1, kt + 1);
#pragma unroll
    for (int ks = 0; ks < 2; ++ks) {
      const int ch = (((ks << 2) | (lane >> 4)) ^ (lane & 7)) << 3;
      bf16x8 af[4], bfr[4];
#pragma unroll
      for (int m = 0; m < 4; ++m)
        af[m] = *reinterpret_cast<const bf16x8*>(&As[cur][wm * 64 + m * 16 + (lane & 15)][ch]);
#pragma unroll
      for (int n = 0; n < 4; ++n)
        bfr[n] = *reinterpret_cast<const bf16x8*>(&Bs[cur][wn * 64 + n * 16 + (lane & 15)][ch]);
#pragma unroll
      for (int m = 0; m < 4; ++m)
#pragma unroll
        for (int n = 0; n < 4; ++n)
          acc[m][n] = __builtin_amdgcn_mfma_f32_16x16x32_bf16(af[m], bfr[n], acc[m][n], 0, 0, 0);
    }
    if (kt + 1 < NK) __syncthreads();
  }

  const int hb = offs[e];
#pragma unroll
  for (int n = 0; n < 4; ++n) {
    const int col = wn * 64 + n * 16 + (lane & 15);
    const int gcol = hbase + nt * 128 + col;
    const float bterm = fcb[e * HDIM + gcol];
#pragma unroll
    for (int m = 0; m < 4; ++m) {
#pragma unroll
      for (int j = 0; j < 4; ++j) {
        const int row = mt * 128 + wm * 64 + m * 16 + ((lane >> 4) << 2) + j;
        float v = acc[m][n][j] + bterm;
        h[(size_t)(hb + row) * HC + (nt * 128 + col)] = f2bf(gelu_tanh(v));
      }
    }
  }
}

// ---------------- GEMM2: scratch[slot] (+)= h @ Wproj^T + b ----------------
__global__ __launch_bounds__(256, 2) void gemm2_kernel(
    const ushort* __restrict__ h, const ushort* __restrict__ wpj,
    const float* __restrict__ pjb, const int* __restrict__ cnt,
    const int* __restrict__ offs, ushort* __restrict__ scratch,
    int hbase, int HC, int first_chunk) {
  const int e = blockIdx.z;
  const int count = cnt[e];
  const int rounded = (count + 127) & ~127;
  const int mt = blockIdx.x;
  if (mt * 128 >= rounded) return;
  const int nt = blockIdx.y;
  const int tid = threadIdx.x;
  const int lane = tid & 63, wave = tid >> 6;
  const int wm = wave >> 1, wn = wave & 1;

  __shared__ ushort As[2][128][64];
  __shared__ ushort Bs[2][128][64];

  const int srow = tid >> 3;
  const int csw8 = (((tid & 7) ^ (srow & 7)) << 3);
  const int dst8 = ((tid & 7) << 3);
  const int hb = offs[e];

  const ushort* abase = h + (size_t)(hb + mt * 128) * HC;
  const ushort* bbase = wpj + (size_t)e * (DDIM * HDIM) +
                        (size_t)(nt * 128) * HDIM + hbase;

  f32x4 acc[4][4];
#pragma unroll
  for (int m = 0; m < 4; ++m)
#pragma unroll
    for (int n = 0; n < 4; ++n)
      acc[m][n] = (f32x4){0.f, 0.f, 0.f, 0.f};

#define G2_STAGE(buf, kt)                                                     \
  {                                                                           \
    const int koff = (kt) * 64;                                               \
    _Pragma("unroll") for (int r = 0; r < 4; ++r) {                           \
      GLOAD16(abase + (size_t)(srow + r * 32) * HC + koff + csw8,             \
              &As[buf][srow + r * 32][dst8]);                                 \
      GLOAD16(bbase + (size_t)(srow + r * 32) * HDIM + koff + csw8,           \
              &Bs[buf][srow + r * 32][dst8]);                                 \
    }                                                                         \
  }

  G2_STAGE(0, 0);
  asm volatile("s_waitcnt vmcnt(0)" ::: "memory");
  __syncthreads();

  const int NK = HC / 64;
  for (int kt = 0; kt < NK; ++kt) {
    const int cur = kt & 1;
    if (kt + 1 < NK) G2_STAGE(cur ^ 1, kt + 1);
#pragma unroll
    for (int ks = 0; ks < 2; ++ks) {
      const int ch = (((ks << 2) | (lane >> 4)) ^ (lane & 7)) << 3;
      bf16x8 af[4], bfr[4];
#pragma unroll
      for (int m = 0; m < 4; ++m)
        af[m] = *reinterpret_cast<const bf16x8*>(&As[cur][wm * 64 + m * 16 + (lane & 15)][ch]);
#pragma unroll
      for (int n = 0; n < 4; ++n)
        bfr[n] = *reinterpret_cast<const bf16x8*>(&Bs[cur][wn * 64 + n * 16 + (lane & 15)][ch]);
#pragma unroll
      for (int m = 0; m < 4; ++m)
#pragma unroll
        for (int n = 0; n < 4; ++n)
          acc[m][n] = __builtin_amdgcn_mfma_f32_16x16x32_bf16(af[m], bfr[n], acc[m][n], 0, 0, 0);
    }
    if (kt + 1 < NK) __syncthreads();
  }

#pragma unroll
  for (int n = 0; n < 4; ++n) {
    const int col = nt * 128 + wn * 64 + n * 16 + (lane & 15);
    const float bterm = pjb[e * DDIM + col];
#pragma unroll
    for (int m = 0; m < 4; ++m) {
#pragma unroll
      for (int j = 0; j < 4; ++j) {
        const size_t row = (size_t)(hb + mt * 128 + wm * 64 + m * 16 + ((lane >> 4) << 2) + j);
        ushort* p = scratch + row * DDIM + col;
        float v = acc[m][n][j];
        if (first_chunk) v += bterm;
        else v += bf2f(*p);
        *p = f2bf(v);
      }
    }
  }
}

// ---------------- combine: out[t] = w1*row1 + w2*row2 ----------------
__global__ __launch_bounds__(256, 8) void combine_kernel(
    const ushort* __restrict__ scratch, const int* __restrict__ offs,
    const int2* __restrict__ slots, const float2* __restrict__ tokw,
    float* __restrict__ out) {
  const int lane = threadIdx.x & 63;
  const int wave = threadIdx.x >> 6;
  const int t = blockIdx.x * 4 + wave;
  int2 s = slots[t];
  float2 w = tokw[t];
  const int r1 = offs[s.x >> 16] + (s.x & 0xFFFF);
  const int r2 = offs[s.y >> 16] + (s.y & 0xFFFF);
  bf16x8 a = *reinterpret_cast<const bf16x8*>(scratch + (size_t)r1 * DDIM + lane * 8);
  bf16x8 b = *reinterpret_cast<const bf16x8*>(scratch + (size_t)r2 * DDIM + lane * 8);
  float r[8];
#pragma unroll
  for (int j = 0; j < 8; ++j)
    r[j] = w.x * bf2f((ushort)a[j]) + w.y * bf2f((ushort)b[j]);
  float4* op = reinterpret_cast<float4*>(out + (size_t)t * DDIM + lane * 8);
  op[0] = make_float4(r[0], r[1], r[2], r[3]);
  op[1] = make_float4(r[4], r[5], r[6], r[7]);
}

extern "C" void kernel_launch(void* const* d_in, const int* in_sizes, int n_in,
                              void* d_out, int out_size, void* d_ws, size_t ws_size,
                              hipStream_t stream) {
  const float* x    = (const float*)d_in[0];
  const float* gw   = (const float*)d_in[1];
  const float* nw   = (const float*)d_in[2];
  const float* bias = (const float*)d_in[3];
  const float* fcw  = (const float*)d_in[4];
  const float* fcb  = (const float*)d_in[5];
  const float* pjw  = (const float*)d_in[6];
  const float* pjb  = (const float*)d_in[7];
  const float* noise = (const float*)d_in[8];
  float* out = (float*)d_out;

  char* ws = (char*)d_ws;
  size_t o = 0;
  auto alloc = [&](size_t bytes) -> char* {
    char* p = ws + o;
    o += (bytes + 255) & ~(size_t)255;
    return p;
  };
  ushort* xbf   = (ushort*)alloc((size_t)TTOK * DDIM * 2);
  ushort* wfcb  = (ushort*)alloc((size_t)NEXP * HDIM * DDIM * 2);
  ushort* wpjb  = (ushort*)alloc((size_t)NEXP * DDIM * HDIM * 2);
  int*    idxl  = (int*)alloc((size_t)NEXP * TTOK * 4);
  int2*   slots = (int2*)alloc((size_t)TTOK * 8);
  float2* tokw  = (float2*)alloc((size_t)TTOK * 8);
  int*    cnt   = (int*)alloc(256);
  int*    offs  = (int*)alloc(256);
  float*  part  = (float*)alloc(34 * GBLK * 4);
  ushort* scr   = (ushort*)alloc((size_t)(2 * TTOK + 1024) * DDIM * 2);
  size_t fixed = o;

  int NCH = 16;
  const int chs[5] = {1, 2, 4, 8, 16};
  for (int ci = 0; ci < 5; ++ci) {
    size_t need = fixed + (size_t)(2 * TTOK + 1024) * (size_t)(HDIM / chs[ci]) * 2;
    if (need <= ws_size) { NCH = chs[ci]; break; }
  }
  const int HC = HDIM / NCH;
  ushort* h = (ushort*)alloc((size_t)(2 * TTOK + 1024) * HC * 2);

  hipMemsetAsync(cnt, 0, 32, stream);

  cvtw_kernel<<<8192, 256, 0, stream>>>(fcw, wfcb, NEXP * HDIM * DDIM / 4);
  cvtw_kernel<<<8192, 256, 0, stream>>>(pjw, wpjb, NEXP * DDIM * HDIM / 4);
  gating_kernel<<<GBLK, 256, 0, stream>>>(x, gw, nw, bias, noise, xbf, cnt, idxl, slots, tokw, part);
  finalize_kernel<<<1, 256, 0, stream>>>(part, cnt, offs, idxl, out + ((size_t)out_size - 1));

  for (int c = 0; c < NCH; ++c) {
    gemm1_kernel<<<dim3(256, HC / 128, NEXP), 256, 0, stream>>>(
        xbf, wfcb, fcb, idxl, cnt, offs, h, c * HC, HC);
    gemm2_kernel<<<dim3(256, 4, NEXP), 256, 0, stream>>>(
        h, wpjb, pjb, cnt, offs, scr, c * HC, HC, c == 0);
  }
  combine_kernel<<<TTOK / 4, 256, 0, stream>>>(scr, offs, slots, tokw, out);
}

// Round 5
// 794.350 us; speedup vs baseline: 2.1010x; 1.1725x over previous
//
#include <hip/hip_runtime.h>
#include <hip/hip_bf16.h>
#include <stdint.h>

#define TTOK 32768
#define DDIM 512
#define HDIM 2048
#define NEXP 8
#define GBLK 1024   // gating blocks; 32 tokens per block (8 per wave)

typedef __attribute__((ext_vector_type(4))) float f32x4;
typedef __attribute__((ext_vector_type(8))) short bf16x8;

#define GLOAD16(gp, lp)                                                      \
  __builtin_amdgcn_global_load_lds(                                          \
      (const __attribute__((address_space(1))) unsigned int*)(gp),           \
      (__attribute__((address_space(3))) unsigned int*)(lp), 16, 0, 0)

__device__ __forceinline__ ushort f2bf(float f) {
  union { float f; uint32_t u; } cv; cv.f = f;
  uint32_t u = cv.u;
  u = u + 0x7fffu + ((u >> 16) & 1u);
  return (ushort)(u >> 16);
}

__device__ __forceinline__ float bf2f(ushort u) {
  union { uint32_t u; float f; } cv; cv.u = ((uint32_t)u) << 16;
  return cv.f;
}

// gelu(v) = 0.5 v (1+tanh(c(v+0.044715 v^3))) = v * sigmoid(2c(v+0.044715 v^3))
// one v_exp + one rcp instead of libm tanhf (~25 VALU). |err| ~1e-7 rel.
__device__ __forceinline__ float gelu_fast(float v) {
  float y = 1.5957691216057308f * (v + 0.044715f * v * v * v);
  return v / (1.0f + __expf(-y));
}

// ---------------- weight fp32 -> bf16 convert ----------------
__global__ __launch_bounds__(256) void cvtw_kernel(const float* __restrict__ src,
                                                   ushort* __restrict__ dst, int n4) {
  int i = blockIdx.x * blockDim.x + threadIdx.x;
  if (i >= n4) return;
  float4 v = reinterpret_cast<const float4*>(src)[i];
  ushort4 o;
  o.x = f2bf(v.x); o.y = f2bf(v.y); o.z = f2bf(v.z); o.w = f2bf(v.w);
  reinterpret_cast<ushort4*>(dst)[i] = o;
}

// ---------------- gating ----------------
// (256,2): VGPR cap 256 so wg/wn (128 regs) stay resident (round-3 lesson:
// (256,4) capped 128 -> spill -> 895MB scratch traffic). 2-token ILP per
// iteration to hide shuffle/transcendental latency at 8 waves/CU.
__global__ __launch_bounds__(256, 2) void gating_kernel(
    const float* __restrict__ x, const float* __restrict__ gw,
    const float* __restrict__ nw, const float* __restrict__ bias,
    const float* __restrict__ noise, ushort* __restrict__ xbf,
    int* __restrict__ cnt, int* __restrict__ idxl,
    int2* __restrict__ slots, float2* __restrict__ tokw,
    float* __restrict__ part) {
  const int tid = threadIdx.x;
  const int lane = tid & 63;
  const int wave = tid >> 6;

  float wg[NEXP][8], wn[NEXP][8];
#pragma unroll
  for (int e = 0; e < NEXP; ++e) {
    const float4* pg = reinterpret_cast<const float4*>(gw + e * DDIM + lane * 8);
    float4 g0 = pg[0], g1 = pg[1];
    wg[e][0] = g0.x; wg[e][1] = g0.y; wg[e][2] = g0.z; wg[e][3] = g0.w;
    wg[e][4] = g1.x; wg[e][5] = g1.y; wg[e][6] = g1.z; wg[e][7] = g1.w;
    const float4* pq = reinterpret_cast<const float4*>(nw + e * DDIM + lane * 8);
    float4 n0 = pq[0], n1 = pq[1];
    wn[e][0] = n0.x; wn[e][1] = n0.y; wn[e][2] = n0.z; wn[e][3] = n0.w;
    wn[e][4] = n1.x; wn[e][5] = n1.y; wn[e][6] = n1.z; wn[e][7] = n1.w;
  }
  float bia[NEXP];
#pragma unroll
  for (int e = 0; e < NEXP; ++e) bia[e] = bias[e];

  float pa_s = 0.f, z_s = 0.f;
  float pm_s[NEXP], imp_s[NEXP], rp_s[NEXP], c1_s[NEXP];
#pragma unroll
  for (int e = 0; e < NEXP; ++e) { pm_s[e] = 0.f; imp_s[e] = 0.f; rp_s[e] = 0.f; c1_s[e] = 0.f; }

  __shared__ int s_i1[32], s_i2[32];
  __shared__ float s_w1[32], s_w2[32];
  __shared__ int lcnt[NEXP], lpos1[32], lpos2[32], gbase[NEXP];

  const int t00 = blockIdx.x * 32 + wave * 8;
  for (int it = 0; it < 8; it += 2) {
    float xv[2][8], nz[2][8];
#pragma unroll
    for (int u = 0; u < 2; ++u) {
      const int t = t00 + it + u;
      const float4* np = reinterpret_cast<const float4*>(noise + (size_t)t * NEXP);
      float4 nz0 = np[0], nz1 = np[1];
      nz[u][0] = nz0.x; nz[u][1] = nz0.y; nz[u][2] = nz0.z; nz[u][3] = nz0.w;
      nz[u][4] = nz1.x; nz[u][5] = nz1.y; nz[u][6] = nz1.z; nz[u][7] = nz1.w;
      const float4* xp = reinterpret_cast<const float4*>(x + (size_t)t * DDIM + lane * 8);
      float4 x0 = xp[0], x1 = xp[1];
      xv[u][0] = x0.x; xv[u][1] = x0.y; xv[u][2] = x0.z; xv[u][3] = x0.w;
      xv[u][4] = x1.x; xv[u][5] = x1.y; xv[u][6] = x1.z; xv[u][7] = x1.w;
      ushort u8[8];
#pragma unroll
      for (int j = 0; j < 8; ++j) u8[j] = f2bf(xv[u][j]);
      uint4 pack;
      pack.x = (uint32_t)u8[0] | ((uint32_t)u8[1] << 16);
      pack.y = (uint32_t)u8[2] | ((uint32_t)u8[3] << 16);
      pack.z = (uint32_t)u8[4] | ((uint32_t)u8[5] << 16);
      pack.w = (uint32_t)u8[6] | ((uint32_t)u8[7] << 16);
      *reinterpret_cast<uint4*>(xbf + (size_t)t * DDIM + lane * 8) = pack;
    }

    float pg[2][NEXP], pn[2][NEXP];
#pragma unroll
    for (int u = 0; u < 2; ++u)
#pragma unroll
      for (int e = 0; e < NEXP; ++e) { pg[u][e] = 0.f; pn[u][e] = 0.f; }
#pragma unroll
    for (int e = 0; e < NEXP; ++e)
#pragma unroll
      for (int j = 0; j < 8; ++j) {
#pragma unroll
        for (int u = 0; u < 2; ++u) {
          pg[u][e] = fmaf(xv[u][j], wg[e][j], pg[u][e]);
          pn[u][e] = fmaf(xv[u][j], wn[e][j], pn[u][e]);
        }
      }
#pragma unroll
    for (int m = 1; m < 64; m <<= 1) {
#pragma unroll
      for (int u = 0; u < 2; ++u)
#pragma unroll
        for (int e = 0; e < NEXP; ++e) {
          pg[u][e] += __shfl_xor(pg[u][e], m);
          pn[u][e] += __shfl_xor(pn[u][e], m);
        }
    }

#pragma unroll
    for (int u = 0; u < 2; ++u) {
      const int t = t00 + it + u;
      // penalty softmax (temperature) - aux only
      float sv[NEXP];
#pragma unroll
      for (int e = 0; e < NEXP; ++e) sv[e] = pg[u][e] * (1.0f / 1.66f);
      float mx = sv[0];
#pragma unroll
      for (int e = 1; e < NEXP; ++e) mx = fmaxf(mx, sv[e]);
      float ssum = 0.f, pvals[NEXP];
#pragma unroll
      for (int e = 0; e < NEXP; ++e) { pvals[e] = __expf(sv[e] - mx); ssum += pvals[e]; }
      float sinv = 1.f / ssum;
#pragma unroll
      for (int e = 0; e < NEXP; ++e) {
        float pe = pvals[e] * sinv;
        pa_s += pe * (1.f - pe);
        pm_s[e] += pe;
      }
      // logsumexp of clean logits - aux only
      float mg = pg[u][0];
#pragma unroll
      for (int e = 1; e < NEXP; ++e) mg = fmaxf(mg, pg[u][e]);
      float es2 = 0.f;
#pragma unroll
      for (int e = 0; e < NEXP; ++e) es2 += __expf(pg[u][e] - mg);
      float lse = mg + __logf(es2);
      z_s += lse * lse;
      // noisy logits; softplus via fast exp/log (err ~1e-7, can't flip top-2)
      float g2[NEXP];
#pragma unroll
      for (int e = 0; e < NEXP; ++e) {
        float s = pn[u][e];
        float sp = fmaxf(s, 0.f) + __logf(1.f + __expf(-fabsf(s)));
        g2[e] = pg[u][e] + nz[u][e] * sp + bia[e];
      }
      float v1 = g2[0]; int i1 = 0;
#pragma unroll
      for (int e = 1; e < NEXP; ++e) if (g2[e] > v1) { v1 = g2[e]; i1 = e; }
      float v2 = -3.4e38f; int i2 = 0;
#pragma unroll
      for (int e = 0; e < NEXP; ++e) if (e != i1 && g2[e] > v2) { v2 = g2[e]; i2 = e; }
      float dd = __expf(v2 - v1);
      float w1 = 1.f / (1.f + dd);
      float w2 = dd / (1.f + dd);
      float mr = g2[0];
#pragma unroll
      for (int e = 1; e < NEXP; ++e) mr = fmaxf(mr, g2[e]);
      float rs = 0.f, er[NEXP];
#pragma unroll
      for (int e = 0; e < NEXP; ++e) { er[e] = __expf(g2[e] - mr); rs += er[e]; }
      float rinv = 1.f / rs;
#pragma unroll
      for (int e = 0; e < NEXP; ++e) rp_s[e] += er[e] * rinv;
#pragma unroll
      for (int e = 0; e < NEXP; ++e) {
        imp_s[e] += (e == i1 ? w1 : 0.f) + (e == i2 ? w2 : 0.f);
        c1_s[e] += (e == i1) ? 1.f : 0.f;
      }
      if (lane == 0) {
        int k = wave * 8 + it + u;
        s_i1[k] = i1; s_i2[k] = i2; s_w1[k] = w1; s_w2[k] = w2;
      }
    }
  }

  __shared__ float red[4][34];
  if (lane == 0) {
    red[wave][0] = pa_s; red[wave][1] = z_s;
#pragma unroll
    for (int e = 0; e < NEXP; ++e) {
      red[wave][2 + e] = pm_s[e];
      red[wave][10 + e] = imp_s[e];
      red[wave][18 + e] = rp_s[e];
      red[wave][26 + e] = c1_s[e];
    }
  }
  if (tid < NEXP) lcnt[tid] = 0;
  __syncthreads();
  if (tid < 34) {
    float s = red[0][tid] + red[1][tid] + red[2][tid] + red[3][tid];
    part[(size_t)tid * GBLK + blockIdx.x] = s;
  }
  if (tid < 32) {
    lpos1[tid] = atomicAdd(&lcnt[s_i1[tid]], 1);
    lpos2[tid] = atomicAdd(&lcnt[s_i2[tid]], 1);
  }
  __syncthreads();
  if (tid < NEXP) gbase[tid] = atomicAdd(&cnt[tid], lcnt[tid]);
  __syncthreads();
  if (tid < 32) {
    int t = blockIdx.x * 32 + tid;
    int e1 = s_i1[tid], p1 = gbase[e1] + lpos1[tid];
    int e2 = s_i2[tid], p2 = gbase[e2] + lpos2[tid];
    idxl[e1 * TTOK + p1] = t;
    idxl[e2 * TTOK + p2] = t;
    slots[t] = make_int2((e1 << 16) | p1, (e2 << 16) | p2);
    tokw[t] = make_float2(s_w1[tid], s_w2[tid]);
  }
}

// ---------------- finalize: aux + offsets + list padding ----------------
__global__ __launch_bounds__(256) void finalize_kernel(
    const float* __restrict__ part, const int* __restrict__ cnt,
    int* __restrict__ offs, int* __restrict__ idxl,
    float* __restrict__ aux_out) {
  __shared__ float sums[34];
  __shared__ float red[4][34];
  __shared__ int roundc[NEXP], base[NEXP];
  const int tid = threadIdx.x;
  const int lane = tid & 63, wave = tid >> 6;

  float loc[34];
#pragma unroll
  for (int s = 0; s < 34; ++s) loc[s] = 0.f;
  for (int b = tid; b < GBLK; b += 256) {
#pragma unroll
    for (int s = 0; s < 34; ++s) loc[s] += part[(size_t)s * GBLK + b];
  }
#pragma unroll
  for (int m = 1; m < 64; m <<= 1) {
#pragma unroll
    for (int s = 0; s < 34; ++s) loc[s] += __shfl_xor(loc[s], m);
  }
  if (lane == 0) {
#pragma unroll
    for (int s = 0; s < 34; ++s) red[wave][s] = loc[s];
  }
  if (tid == 0) {
    int acc = 0;
    for (int e = 0; e < NEXP; ++e) {
      int r = (cnt[e] + 127) & ~127;
      roundc[e] = r; base[e] = acc; acc += r;
    }
  }
  __syncthreads();
  if (tid < 34) sums[tid] = red[0][tid] + red[1][tid] + red[2][tid] + red[3][tid];
  __syncthreads();
  for (int i = tid; i < NEXP * 128; i += 256) {
    int e = i >> 7, k = i & 127;
    int pos = cnt[e] + k;
    if (pos < roundc[e]) idxl[e * TTOK + pos] = 0;
  }
  if (tid < NEXP) offs[tid] = base[tid];
  if (tid == 0) {
    const float Tf = (float)TTOK;
    float pa = sums[0] / (Tf * 8.f);
    float pbm = 0.f;
    for (int e = 0; e < NEXP; ++e) { float pm = sums[2 + e] / Tf; pbm += pm * (1.f - pm); }
    float pb = 1.f / 8.f - pbm / 8.f;
    float penalty = (pa + pb) * 0.01f;
    float z = 0.001f * sums[1] / Tf;
    float mean = 0.f;
    for (int e = 0; e < NEXP; ++e) mean += sums[10 + e];
    mean /= 8.f;
    float var = 0.f;
    for (int e = 0; e < NEXP; ++e) { float d = sums[10 + e] - mean; var += d * d; }
    var /= 8.f;
    float il = 0.01f * var / (mean * mean);
    float ld = 0.f;
    for (int e = 0; e < NEXP; ++e) ld += (sums[26 + e] / Tf) * (sums[18 + e] / Tf);
    ld *= 0.01f * 8.f;
    aux_out[0] = penalty + z + il + ld;
  }
}

// ============ GEMM kernels: global_load_lds + XOR-swizzled LDS, 2-phase ======
// LDS layout: [128][64] ushort, linear (no pad). Slot s of row r holds global
// K-chunk (s ^ (r&7)) (16B chunks). Staged by pre-swizzling the GLOBAL source
// chunk; ds_read applies the same XOR. (both-sides-or-neither, m201 pattern)

// ---------------- GEMM1: h = gelu(x[idx] @ Wfc^T + b) ----------------
__global__ __launch_bounds__(256, 2) void gemm1_kernel(
    const ushort* __restrict__ xbf, const ushort* __restrict__ wfc,
    const float* __restrict__ fcb, const int* __restrict__ idxl,
    const int* __restrict__ cnt, const int* __restrict__ offs,
    ushort* __restrict__ h, int hbase, int HC) {
  const int e = blockIdx.z;
  const int count = cnt[e];
  const int rounded = (count + 127) & ~127;
  const int mt = blockIdx.x;
  if (mt * 128 >= rounded) return;
  const int nt = blockIdx.y;
  const int tid = threadIdx.x;
  const int lane = tid & 63, wave = tid >> 6;
  const int wm = wave >> 1, wn = wave & 1;

  __shared__ ushort As[2][128][64];
  __shared__ ushort Bs[2][128][64];

  const int srow = tid >> 3;                      // staging row 0..31
  const int csw8 = (((tid & 7) ^ (srow & 7)) << 3);  // swizzled global chunk (ushorts)
  const int dst8 = ((tid & 7) << 3);                 // linear LDS chunk (ushorts)

  int gA[4];
  const ushort* bbase = wfc + (size_t)e * (HDIM * DDIM) +
                        (size_t)(hbase + nt * 128) * DDIM;
#pragma unroll
  for (int r = 0; r < 4; ++r)
    gA[r] = idxl[e * TTOK + mt * 128 + srow + r * 32];

  f32x4 acc[4][4];
#pragma unroll
  for (int m = 0; m < 4; ++m)
#pragma unroll
    for (int n = 0; n < 4; ++n)
      acc[m][n] = (f32x4){0.f, 0.f, 0.f, 0.f};

#define G1_STAGE(buf, kt)                                                     \
  {                                                                           \
    const int koff = (kt) * 64;                                               \
    _Pragma("unroll") for (int r = 0; r < 4; ++r) {                           \
      GLOAD16(xbf + (size_t)gA[r] * DDIM + koff + csw8,                       \
              &As[buf][srow + r * 32][dst8]);                                 \
      GLOAD16(bbase + (size_t)(srow + r * 32) * DDIM + koff + csw8,           \
              &Bs[buf][srow + r * 32][dst8]);                                 \
    }                                                                         \
  }

  G1_STAGE(0, 0);
  asm volatile("s_waitcnt vmcnt(0)" ::: "memory");
  __syncthreads();

  const int NK = DDIM / 64;
  for (int kt = 0; kt < NK; ++kt) {
    const int cur = kt & 1;
    if (kt + 1 < NK) G1_STAGE(cur ^ 1, kt + 1);
#pragma unroll
    for (int ks = 0; ks < 2; ++ks) {
      const int ch = (((ks << 2) | (lane >> 4)) ^ (lane & 7)) << 3;
      bf16x8 af[4], bfr[4];
#pragma unroll
      for (int m = 0; m < 4; ++m)
        af[m] = *reinterpret_cast<const bf16x8*>(&As[cur][wm * 64 + m * 16 + (lane & 15)][ch]);
#pragma unroll
      for (int n = 0; n < 4; ++n)
        bfr[n] = *reinterpret_cast<const bf16x8*>(&Bs[cur][wn * 64 + n * 16 + (lane & 15)][ch]);
#pragma unroll
      for (int m = 0; m < 4; ++m)
#pragma unroll
        for (int n = 0; n < 4; ++n)
          acc[m][n] = __builtin_amdgcn_mfma_f32_16x16x32_bf16(af[m], bfr[n], acc[m][n], 0, 0, 0);
    }
    if (kt + 1 < NK) __syncthreads();
  }

  const int hb = offs[e];
#pragma unroll
  for (int n = 0; n < 4; ++n) {
    const int col = wn * 64 + n * 16 + (lane & 15);
    const int gcol = hbase + nt * 128 + col;
    const float bterm = fcb[e * HDIM + gcol];
#pragma unroll
    for (int m = 0; m < 4; ++m) {
#pragma unroll
      for (int j = 0; j < 4; ++j) {
        const int row = mt * 128 + wm * 64 + m * 16 + ((lane >> 4) << 2) + j;
        float v = acc[m][n][j] + bterm;
        h[(size_t)(hb + row) * HC + (nt * 128 + col)] = f2bf(gelu_fast(v));
      }
    }
  }
}

// ---------------- GEMM2: scratch[slot] (+)= h @ Wproj^T + b ----------------
__global__ __launch_bounds__(256, 2) void gemm2_kernel(
    const ushort* __restrict__ h, const ushort* __restrict__ wpj,
    const float* __restrict__ pjb, const int* __restrict__ cnt,
    const int* __restrict__ offs, ushort* __restrict__ scratch,
    int hbase, int HC, int first_chunk) {
  const int e = blockIdx.z;
  const int count = cnt[e];
  const int rounded = (count + 127) & ~127;
  const int mt = blockIdx.x;
  if (mt * 128 >= rounded) return;
  const int nt = blockIdx.y;
  const int tid = threadIdx.x;
  const int lane = tid & 63, wave = tid >> 6;
  const int wm = wave >> 1, wn = wave & 1;

  __shared__ ushort As[2][128][64];
  __shared__ ushort Bs[2][128][64];

  const int srow = tid >> 3;
  const int csw8 = (((tid & 7) ^ (srow & 7)) << 3);
  const int dst8 = ((tid & 7) << 3);
  const int hb = offs[e];

  const ushort* abase = h + (size_t)(hb + mt * 128) * HC;
  const ushort* bbase = wpj + (size_t)e * (DDIM * HDIM) +
                        (size_t)(nt * 128) * HDIM + hbase;

  f32x4 acc[4][4];
#pragma unroll
  for (int m = 0; m < 4; ++m)
#pragma unroll
    for (int n = 0; n < 4; ++n)
      acc[m][n] = (f32x4){0.f, 0.f, 0.f, 0.f};

#define G2_STAGE(buf, kt)                                                     \
  {                                                                           \
    const int koff = (kt) * 64;                                               \
    _Pragma("unroll") for (int r = 0; r < 4; ++r) {                           \
      GLOAD16(abase + (size_t)(srow + r * 32) * HC + koff + csw8,             \
              &As[buf][srow + r * 32][dst8]);                                 \
      GLOAD16(bbase + (size_t)(srow + r * 32) * HDIM + koff + csw8,           \
              &Bs[buf][srow + r * 32][dst8]);                                 \
    }                                                                         \
  }

  G2_STAGE(0, 0);
  asm volatile("s_waitcnt vmcnt(0)" ::: "memory");
  __syncthreads();

  const int NK = HC / 64;
  for (int kt = 0; kt < NK; ++kt) {
    const int cur = kt & 1;
    if (kt + 1 < NK) G2_STAGE(cur ^ 1, kt + 1);
#pragma unroll
    for (int ks = 0; ks < 2; ++ks) {
      const int ch = (((ks << 2) | (lane >> 4)) ^ (lane & 7)) << 3;
      bf16x8 af[4], bfr[4];
#pragma unroll
      for (int m = 0; m < 4; ++m)
        af[m] = *reinterpret_cast<const bf16x8*>(&As[cur][wm * 64 + m * 16 + (lane & 15)][ch]);
#pragma unroll
      for (int n = 0; n < 4; ++n)
        bfr[n] = *reinterpret_cast<const bf16x8*>(&Bs[cur][wn * 64 + n * 16 + (lane & 15)][ch]);
#pragma unroll
      for (int m = 0; m < 4; ++m)
#pragma unroll
        for (int n = 0; n < 4; ++n)
          acc[m][n] = __builtin_amdgcn_mfma_f32_16x16x32_bf16(af[m], bfr[n], acc[m][n], 0, 0, 0);
    }
    if (kt + 1 < NK) __syncthreads();
  }

#pragma unroll
  for (int n = 0; n < 4; ++n) {
    const int col = nt * 128 + wn * 64 + n * 16 + (lane & 15);
    const float bterm = pjb[e * DDIM + col];
#pragma unroll
    for (int m = 0; m < 4; ++m) {
#pragma unroll
      for (int j = 0; j < 4; ++j) {
        const size_t row = (size_t)(hb + mt * 128 + wm * 64 + m * 16 + ((lane >> 4) << 2) + j);
        ushort* p = scratch + row * DDIM + col;
        float v = acc[m][n][j];
        if (first_chunk) v += bterm;
        else v += bf2f(*p);
        *p = f2bf(v);
      }
    }
  }
}

// ---------------- combine: out[t] = w1*row1 + w2*row2 ----------------
__global__ __launch_bounds__(256, 8) void combine_kernel(
    const ushort* __restrict__ scratch, const int* __restrict__ offs,
    const int2* __restrict__ slots, const float2* __restrict__ tokw,
    float* __restrict__ out) {
  const int lane = threadIdx.x & 63;
  const int wave = threadIdx.x >> 6;
  const int t = blockIdx.x * 4 + wave;
  int2 s = slots[t];
  float2 w = tokw[t];
  const int r1 = offs[s.x >> 16] + (s.x & 0xFFFF);
  const int r2 = offs[s.y >> 16] + (s.y & 0xFFFF);
  bf16x8 a = *reinterpret_cast<const bf16x8*>(scratch + (size_t)r1 * DDIM + lane * 8);
  bf16x8 b = *reinterpret_cast<const bf16x8*>(scratch + (size_t)r2 * DDIM + lane * 8);
  float r[8];
#pragma unroll
  for (int j = 0; j < 8; ++j)
    r[j] = w.x * bf2f((ushort)a[j]) + w.y * bf2f((ushort)b[j]);
  float4* op = reinterpret_cast<float4*>(out + (size_t)t * DDIM + lane * 8);
  op[0] = make_float4(r[0], r[1], r[2], r[3]);
  op[1] = make_float4(r[4], r[5], r[6], r[7]);
}

extern "C" void kernel_launch(void* const* d_in, const int* in_sizes, int n_in,
                              void* d_out, int out_size, void* d_ws, size_t ws_size,
                              hipStream_t stream) {
  const float* x    = (const float*)d_in[0];
  const float* gw   = (const float*)d_in[1];
  const float* nw   = (const float*)d_in[2];
  const float* bias = (const float*)d_in[3];
  const float* fcw  = (const float*)d_in[4];
  const float* fcb  = (const float*)d_in[5];
  const float* pjw  = (const float*)d_in[6];
  const float* pjb  = (const float*)d_in[7];
  const float* noise = (const float*)d_in[8];
  float* out = (float*)d_out;

  char* ws = (char*)d_ws;
  size_t o = 0;
  auto alloc = [&](size_t bytes) -> char* {
    char* p = ws + o;
    o += (bytes + 255) & ~(size_t)255;
    return p;
  };
  ushort* xbf   = (ushort*)alloc((size_t)TTOK * DDIM * 2);
  ushort* wfcb  = (ushort*)alloc((size_t)NEXP * HDIM * DDIM * 2);
  ushort* wpjb  = (ushort*)alloc((size_t)NEXP * DDIM * HDIM * 2);
  int*    idxl  = (int*)alloc((size_t)NEXP * TTOK * 4);
  int2*   slots = (int2*)alloc((size_t)TTOK * 8);
  float2* tokw  = (float2*)alloc((size_t)TTOK * 8);
  int*    cnt   = (int*)alloc(256);
  int*    offs  = (int*)alloc(256);
  float*  part  = (float*)alloc(34 * GBLK * 4);
  ushort* scr   = (ushort*)alloc((size_t)(2 * TTOK + 1024) * DDIM * 2);
  size_t fixed = o;

  int NCH = 16;
  const int chs[5] = {1, 2, 4, 8, 16};
  for (int ci = 0; ci < 5; ++ci) {
    size_t need = fixed + (size_t)(2 * TTOK + 1024) * (size_t)(HDIM / chs[ci]) * 2;
    if (need <= ws_size) { NCH = chs[ci]; break; }
  }
  const int HC = HDIM / NCH;
  ushort* h = (ushort*)alloc((size_t)(2 * TTOK + 1024) * HC * 2);

  hipMemsetAsync(cnt, 0, 32, stream);

  cvtw_kernel<<<8192, 256, 0, stream>>>(fcw, wfcb, NEXP * HDIM * DDIM / 4);
  cvtw_kernel<<<8192, 256, 0, stream>>>(pjw, wpjb, NEXP * DDIM * HDIM / 4);
  gating_kernel<<<GBLK, 256, 0, stream>>>(x, gw, nw, bias, noise, xbf, cnt, idxl, slots, tokw, part);
  finalize_kernel<<<1, 256, 0, stream>>>(part, cnt, offs, idxl, out + ((size_t)out_size - 1));

  for (int c = 0; c < NCH; ++c) {
    gemm1_kernel<<<dim3(256, HC / 128, NEXP), 256, 0, stream>>>(
        xbf, wfcb, fcb, idxl, cnt, offs, h, c * HC, HC);
    gemm2_kernel<<<dim3(256, 4, NEXP), 256, 0, stream>>>(
        h, wpjb, pjb, cnt, offs, scr, c * HC, HC, c == 0);
  }
  combine_kernel<<<TTOK / 4, 256, 0, stream>>>(scr, offs, slots, tokw, out);
}